// Round 1
// baseline (4174.025 us; speedup 1.0000x reference)
//
#include <hip/hip_runtime.h>
#include <math.h>

#define NN 100000
#define EE 1600000
#define GG 256
#define TBINS 8192
#define EPSV 1e-5f

// ---------- embedding table: emb[95][64] = atom_table @ W_embed + b ----------
__global__ void k_emb(const float* __restrict__ at, const float* __restrict__ We,
                      const float* __restrict__ be, float* __restrict__ emb) {
    int t = blockIdx.x, c = threadIdx.x;
    float acc = be[c];
    const float* ar = at + t * 200;
    for (int k = 0; k < 200; k++) acc = fmaf(ar[k], We[k * 64 + c], acc);
    emb[t * 64 + c] = acc;
}

// ---------- x[n] = emb[type[n]] ----------
__global__ void k_ninit(const int* __restrict__ types, const float* __restrict__ emb,
                        float* __restrict__ x) {
    int i = blockIdx.x * 4 + (threadIdx.x >> 6);
    int c = threadIdx.x & 63;
    x[i * 64 + c] = emb[types[i] * 64 + c];
}

// ---------- distance->e_lin lerp table, paired layout: T2[l][i][c] = {col c, col c+64} ----------
__global__ void k_table(const float* __restrict__ We, const float* __restrict__ be,
                        float2* __restrict__ T2) {
    int i = blockIdx.x, l = blockIdx.y, c = threadIdx.x;  // block = 64 threads
    __shared__ float rbf[40];
    float d = i * (8.0f / (TBINS - 1));
    if (c < 40) { float u = d - c * (8.0f / 39.0f); rbf[c] = expf(-4.875f * u * u); }
    __syncthreads();
    const float* W = We + l * 40 * 128;
    float a1 = be[l * 128 + c], a2 = be[l * 128 + 64 + c];
    for (int k = 0; k < 40; k++) {
        a1 = fmaf(rbf[k], W[k * 128 + c], a1);
        a2 = fmaf(rbf[k], W[k * 128 + 64 + c], a2);
    }
    T2[((size_t)l * TBINS + i) * 64 + c] = make_float2(a1, a2);
}

// ---------- node GEMM: h_src|h_dst = x @ [Wsrc|Wdst] + b, stored in paired (c, c+64) layout ----------
__global__ __launch_bounds__(256) void k_gemm(const float* __restrict__ x,
        const float* __restrict__ Ws, const float* __restrict__ bs,
        const float* __restrict__ Wd, const float* __restrict__ bd,
        float* __restrict__ hs2, float* __restrict__ hd2, int l) {
    __shared__ float Wc[64 * 256];  // combined [k][0..127 src | 128..255 dst], 64KB
    int tid = threadIdx.x;
    const float* WsL = Ws + l * 64 * 128;
    const float* WdL = Wd + l * 64 * 128;
    for (int idx = tid; idx < 64 * 128; idx += 256) {
        int k = idx >> 7, c = idx & 127;
        Wc[k * 256 + c] = WsL[idx];
        Wc[k * 256 + 128 + c] = WdL[idx];
    }
    int w = tid >> 6, lane = tid & 63;
    int c4 = lane * 4;
    float4 bias;
    {
        float bv[4];
        #pragma unroll
        for (int j = 0; j < 4; j++) {
            int cc = c4 + j;
            bv[j] = (cc < 128) ? bs[l * 128 + cc] : bd[l * 128 + cc - 128];
        }
        bias = make_float4(bv[0], bv[1], bv[2], bv[3]);
    }
    __syncthreads();
    for (int r0 = blockIdx.x * 16; r0 < NN; r0 += gridDim.x * 16) {
        int rb = r0 + w * 4;  // this wave's 4 rows
        float4 acc[4];
        #pragma unroll
        for (int j = 0; j < 4; j++) acc[j] = bias;
        #pragma unroll
        for (int k4 = 0; k4 < 64; k4 += 4) {
            float4 xv[4];
            #pragma unroll
            for (int j = 0; j < 4; j++)
                xv[j] = *(const float4*)(x + (size_t)(rb + j) * 64 + k4);
            #pragma unroll
            for (int kk = 0; kk < 4; kk++) {
                float4 wv = *(const float4*)&Wc[(k4 + kk) * 256 + c4];
                #pragma unroll
                for (int j = 0; j < 4; j++) {
                    float xs = (kk == 0) ? xv[j].x : (kk == 1) ? xv[j].y : (kk == 2) ? xv[j].z : xv[j].w;
                    acc[j].x = fmaf(xs, wv.x, acc[j].x);
                    acc[j].y = fmaf(xs, wv.y, acc[j].y);
                    acc[j].z = fmaf(xs, wv.z, acc[j].z);
                    acc[j].w = fmaf(xs, wv.w, acc[j].w);
                }
            }
        }
        // paired store: quadrant q of combined col space -> (hs2|hd2).(x|y)
        int q = c4 >> 6, cb = c4 & 63, comp = q & 1;
        float* basearr = (q < 2) ? hs2 : hd2;
        #pragma unroll
        for (int j = 0; j < 4; j++) {
            float* p = basearr + ((size_t)(rb + j) * 64 + cb) * 2 + comp;
            p[0] = acc[j].x; p[2] = acc[j].y; p[4] = acc[j].z; p[6] = acc[j].w;
        }
    }
}

// ---------- edge pass 1: per-column sum / sumsq of m over all edges ----------
__global__ __launch_bounds__(256) void k_estats(const float2* __restrict__ hs2,
        const float2* __restrict__ hd2, const float2* __restrict__ T2l,
        const int* __restrict__ src, const int* __restrict__ dst,
        const float* __restrict__ dist, float* __restrict__ stats) {
    int lane = threadIdx.x & 63, grp = threadIdx.x >> 6;
    float s1 = 0, q1 = 0, s2 = 0, q2 = 0;
    for (int e = blockIdx.x * 4 + grp; e < EE; e += gridDim.x * 4) {
        int s = src[e], d = dst[e];
        float t = dist[e] * ((TBINS - 1) / 8.0f);
        int i = (int)t; i = (i > TBINS - 2) ? (TBINS - 2) : i;
        float f = t - i;
        float2 hsv = hs2[s * 64 + lane];
        float2 hdv = hd2[d * 64 + lane];
        float2 t0 = T2l[(size_t)i * 64 + lane];
        float2 t1 = T2l[(size_t)(i + 1) * 64 + lane];
        float m1 = hsv.x + hdv.x + t0.x + f * (t1.x - t0.x);
        float m2 = hsv.y + hdv.y + t0.y + f * (t1.y - t0.y);
        s1 += m1; q1 += m1 * m1; s2 += m2; q2 += m2 * m2;
    }
    __shared__ float red[4][4][64];
    red[grp][0][lane] = s1; red[grp][1][lane] = s2;
    red[grp][2][lane] = q1; red[grp][3][lane] = q2;
    __syncthreads();
    if (threadIdx.x < 64) {
        float a0 = 0, a1 = 0, a2 = 0, a3 = 0;
        #pragma unroll
        for (int g = 0; g < 4; g++) {
            a0 += red[g][0][lane]; a1 += red[g][1][lane];
            a2 += red[g][2][lane]; a3 += red[g][3][lane];
        }
        atomicAdd(&stats[lane], a0);
        atomicAdd(&stats[64 + lane], a1);
        atomicAdd(&stats[128 + lane], a2);
        atomicAdd(&stats[192 + lane], a3);
    }
}

// ---------- finalize msg batchnorm -> affine a,bb per column ----------
__global__ void k_bn1(float* __restrict__ stats, const float* __restrict__ g,
                      const float* __restrict__ b, int l) {
    int c = threadIdx.x;  // 128
    float mean = stats[c] * (1.0f / EE);
    float var = stats[128 + c] * (1.0f / EE) - mean * mean;
    float a = g[l * 128 + c] * rsqrtf(var + EPSV);
    stats[256 + c] = a;
    stats[384 + c] = b[l * 128 + c] - mean * a;
}

// ---------- edge pass 2: normalize, gate, scatter-add to dst ----------
__global__ __launch_bounds__(256) void k_eapply(const float2* __restrict__ hs2,
        const float2* __restrict__ hd2, const float2* __restrict__ T2l,
        const int* __restrict__ src, const int* __restrict__ dst,
        const float* __restrict__ dist, const float* __restrict__ stats,
        float* __restrict__ hacc) {
    int lane = threadIdx.x & 63, grp = threadIdx.x >> 6;
    float a1 = stats[256 + lane], a2 = stats[256 + 64 + lane];
    float b1 = stats[384 + lane], b2 = stats[384 + 64 + lane];
    for (int e = blockIdx.x * 4 + grp; e < EE; e += gridDim.x * 4) {
        int s = src[e], d = dst[e];
        float t = dist[e] * ((TBINS - 1) / 8.0f);
        int i = (int)t; i = (i > TBINS - 2) ? (TBINS - 2) : i;
        float f = t - i;
        float2 hsv = hs2[s * 64 + lane];
        float2 hdv = hd2[d * 64 + lane];
        float2 t0 = T2l[(size_t)i * 64 + lane];
        float2 t1 = T2l[(size_t)(i + 1) * 64 + lane];
        float m1 = hsv.x + hdv.x + t0.x + f * (t1.x - t0.x);
        float m2 = hsv.y + hdv.y + t0.y + f * (t1.y - t0.y);
        float mn1 = fmaf(a1, m1, b1);
        float mn2 = fmaf(a2, m2, b2);
        float sig = 1.0f / (1.0f + __expf(-mn1));
        float sp = fmaxf(mn2, 0.0f) + log1pf(__expf(-fabsf(mn2)));
        atomicAdd(&hacc[(size_t)d * 64 + lane], sig * sp);
    }
}

// ---------- node bn stats over hacc ----------
__global__ __launch_bounds__(256) void k_nstats(const float* __restrict__ hacc,
                                                float* __restrict__ nstats) {
    int lane = threadIdx.x & 63, grp = threadIdx.x >> 6;
    float s = 0, q = 0;
    for (int r = blockIdx.x * 4 + grp; r < NN; r += gridDim.x * 4) {
        float v = hacc[(size_t)r * 64 + lane];
        s += v; q += v * v;
    }
    __shared__ float red[4][2][64];
    red[grp][0][lane] = s; red[grp][1][lane] = q;
    __syncthreads();
    if (threadIdx.x < 64) {
        float a0 = 0, a1 = 0;
        #pragma unroll
        for (int g = 0; g < 4; g++) { a0 += red[g][0][lane]; a1 += red[g][1][lane]; }
        atomicAdd(&nstats[lane], a0);
        atomicAdd(&nstats[64 + lane], a1);
    }
}

__global__ void k_bn2(float* __restrict__ nstats, const float* __restrict__ g,
                      const float* __restrict__ b, int l) {
    int c = threadIdx.x;  // 64
    float mean = nstats[c] * (1.0f / NN);
    float var = nstats[64 + c] * (1.0f / NN) - mean * mean;
    float a = g[l * 64 + c] * rsqrtf(var + EPSV);
    nstats[128 + c] = a;
    nstats[192 + c] = b[l * 64 + c] - mean * a;
}

// ---------- x = softplus(x + bn(hacc)) ----------
__global__ void k_update(float* __restrict__ x, const float* __restrict__ hacc,
                         const float* __restrict__ nstats) {
    int i = blockIdx.x * 4 + (threadIdx.x >> 6);
    int c = threadIdx.x & 63;
    float v = x[i * 64 + c] + fmaf(nstats[128 + c], hacc[i * 64 + c], nstats[192 + c]);
    x[i * 64 + c] = fmaxf(v, 0.0f) + log1pf(__expf(-fabsf(v)));
}

// ---------- readout ----------
__global__ void k_pool(const float* __restrict__ x, const int* __restrict__ gid,
                       float* __restrict__ pooled, float* __restrict__ counts) {
    int i = blockIdx.x * 4 + (threadIdx.x >> 6);
    int c = threadIdx.x & 63;
    int g = gid[i];
    atomicAdd(&pooled[g * 64 + c], x[i * 64 + c]);
    if (c == 0) atomicAdd(&counts[g], 1.0f);
}

__global__ void k_out(const float* __restrict__ pooled, const float* __restrict__ counts,
                      float* __restrict__ out) {
    int g = blockIdx.x, c = threadIdx.x;
    out[g * 64 + c] = pooled[g * 64 + c] / fmaxf(counts[g], 1.0f);
}

extern "C" void kernel_launch(void* const* d_in, const int* in_sizes, int n_in,
                              void* d_out, int out_size, void* d_ws, size_t ws_size,
                              hipStream_t stream) {
    const int* atom_types   = (const int*)d_in[0];
    const float* distances  = (const float*)d_in[1];
    const int* src          = (const int*)d_in[2];
    const int* dst          = (const int*)d_in[3];
    const int* gid          = (const int*)d_in[4];
    const float* atom_table = (const float*)d_in[6];
    const float* W_embed    = (const float*)d_in[7];
    const float* b_embed    = (const float*)d_in[8];
    const float* W_src      = (const float*)d_in[9];
    const float* b_src      = (const float*)d_in[10];
    const float* W_dst      = (const float*)d_in[11];
    const float* b_dst      = (const float*)d_in[12];
    const float* W_edge     = (const float*)d_in[13];
    const float* b_edge     = (const float*)d_in[14];
    const float* g_msg      = (const float*)d_in[15];
    const float* beta_msg   = (const float*)d_in[16];
    const float* g_bn       = (const float*)d_in[17];
    const float* beta_bn    = (const float*)d_in[18];
    float* out = (float*)d_out;

    float* ws     = (float*)d_ws;
    float* x      = ws;                            // N*64
    float* hs2    = x + (size_t)NN * 64;           // N*128 (paired)
    float* hd2    = hs2 + (size_t)NN * 128;        // N*128 (paired)
    float* hacc   = hd2 + (size_t)NN * 128;        // N*64
    float* T2     = hacc + (size_t)NN * 64;        // L*TBINS*128 (paired)
    float* emb    = T2 + (size_t)3 * TBINS * 128;  // 95*64
    float* stats  = emb + 95 * 64;                 // 512
    float* nstats = stats + 512;                   // 256
    float* pooled = nstats + 256;                  // G*64
    float* counts = pooled + GG * 64;              // G

    k_emb<<<95, 64, 0, stream>>>(atom_table, W_embed, b_embed, emb);
    k_table<<<dim3(TBINS, 3), 64, 0, stream>>>(W_edge, b_edge, (float2*)T2);
    k_ninit<<<NN / 4, 256, 0, stream>>>(atom_types, emb, x);

    for (int l = 0; l < 3; l++) {
        hipMemsetAsync(stats, 0, 768 * sizeof(float), stream);
        hipMemsetAsync(hacc, 0, (size_t)NN * 64 * sizeof(float), stream);
        k_gemm<<<512, 256, 0, stream>>>(x, W_src, b_src, W_dst, b_dst, hs2, hd2, l);
        const float2* T2l = (const float2*)T2 + (size_t)l * TBINS * 64;
        k_estats<<<2048, 256, 0, stream>>>((const float2*)hs2, (const float2*)hd2, T2l,
                                           src, dst, distances, stats);
        k_bn1<<<1, 128, 0, stream>>>(stats, g_msg, beta_msg, l);
        k_eapply<<<2048, 256, 0, stream>>>((const float2*)hs2, (const float2*)hd2, T2l,
                                           src, dst, distances, stats, hacc);
        k_nstats<<<2048, 256, 0, stream>>>(hacc, nstats);
        k_bn2<<<1, 64, 0, stream>>>(nstats, g_bn, beta_bn, l);
        k_update<<<NN / 4, 256, 0, stream>>>(x, hacc, nstats);
    }

    hipMemsetAsync(pooled, 0, (GG * 64 + GG) * sizeof(float), stream);
    k_pool<<<NN / 4, 256, 0, stream>>>(x, gid, pooled, counts);
    k_out<<<GG, 64, 0, stream>>>(pooled, counts, out);
}

// Round 2
// 3526.218 us; speedup vs baseline: 1.1837x; 1.1837x over previous
//
#include <hip/hip_runtime.h>
#include <math.h>

#define NN 100000
#define EE 1600000
#define GG 256
#define TB 8192
#define EPSV 1e-5f

__device__ __forceinline__ float blo(unsigned u) { return __uint_as_float(u << 16); }
__device__ __forceinline__ float bhi(unsigned u) { return __uint_as_float(u & 0xffff0000u); }
__device__ __forceinline__ unsigned bfp(float a, float b) {  // pack (lo=a, hi=b) bf16 RNE
    unsigned ua = __float_as_uint(a), ub = __float_as_uint(b);
    ua += 0x7fffu + ((ua >> 16) & 1u);
    ub += 0x7fffu + ((ub >> 16) & 1u);
    return (ua >> 16) | (ub & 0xffff0000u);
}

// ---------- embedding table: emb[95][64] = atom_table @ W_embed + b ----------
__global__ void k_emb(const float* __restrict__ at, const float* __restrict__ We,
                      const float* __restrict__ be, float* __restrict__ emb) {
    int t = blockIdx.x, c = threadIdx.x;
    float acc = be[c];
    const float* ar = at + t * 200;
    for (int k = 0; k < 200; k++) acc = fmaf(ar[k], We[k * 64 + c], acc);
    emb[t * 64 + c] = acc;
}

// ---------- x[n] = emb[type[n]] ----------
__global__ void k_ninit(const int* __restrict__ types, const float* __restrict__ emb,
                        float* __restrict__ x) {
    int i = blockIdx.x * 4 + (threadIdx.x >> 6);
    int c = threadIdx.x & 63;
    x[i * 64 + c] = emb[types[i] * 64 + c];
}

// ---------- distance table (nearest bin), bf16 pair packed: Tp[l][i][c] = {col c, col c+64} ----------
__global__ void k_table(const float* __restrict__ We, const float* __restrict__ be,
                        unsigned* __restrict__ Tp) {
    int i = blockIdx.x, l = blockIdx.y, c = threadIdx.x;  // 64 threads
    __shared__ float rbf[40];
    float d = i * (1.0f / 1024.0f);  // bin center, matches bin = round(d*1024)
    if (c < 40) { float u = d - c * (8.0f / 39.0f); rbf[c] = expf(-4.875f * u * u); }
    __syncthreads();
    const float* W = We + l * 40 * 128;
    float a1 = be[l * 128 + c], a2 = be[l * 128 + 64 + c];
    for (int k = 0; k < 40; k++) {
        a1 = fmaf(rbf[k], W[k * 128 + c], a1);
        a2 = fmaf(rbf[k], W[k * 128 + 64 + c], a2);
    }
    Tp[((size_t)l * TB + i) * 64 + c] = bfp(a1, a2);
}

// ---------- CSR build ----------
__global__ void k_hist(const int* __restrict__ dst, int* __restrict__ deg) {
    int e = blockIdx.x * 256 + threadIdx.x;
    if (e < EE) atomicAdd(&deg[dst[e]], 1);
}

// per-chunk exclusive scan (chunk = 1024)
__global__ __launch_bounds__(1024) void k_scanA(const int* __restrict__ deg,
                                                int* __restrict__ offs, int* __restrict__ csum) {
    __shared__ int tmp[1024];
    int idx = blockIdx.x * 1024 + threadIdx.x;
    int v = (idx < NN) ? deg[idx] : 0;
    tmp[threadIdx.x] = v;
    __syncthreads();
    for (int off = 1; off < 1024; off <<= 1) {
        int t = (threadIdx.x >= off) ? tmp[threadIdx.x - off] : 0;
        __syncthreads();
        tmp[threadIdx.x] += t;
        __syncthreads();
    }
    if (idx < NN) offs[idx] = tmp[threadIdx.x] - v;  // chunk-local exclusive
    if (threadIdx.x == 1023) csum[blockIdx.x] = tmp[1023];
}

__global__ __launch_bounds__(128) void k_scanB(int* __restrict__ csum, int* __restrict__ cbase,
                                               int nchunk) {
    __shared__ int tmp[128];
    int v = (threadIdx.x < nchunk) ? csum[threadIdx.x] : 0;
    tmp[threadIdx.x] = v;
    __syncthreads();
    for (int off = 1; off < 128; off <<= 1) {
        int t = (threadIdx.x >= off) ? tmp[threadIdx.x - off] : 0;
        __syncthreads();
        tmp[threadIdx.x] += t;
        __syncthreads();
    }
    cbase[threadIdx.x] = tmp[threadIdx.x] - v;  // exclusive
    if (threadIdx.x == 127) cbase[127 + 1] = 0;  // unused
}

__global__ void k_scanC(int* __restrict__ offs, const int* __restrict__ cbase,
                        const int* __restrict__ csum, int nchunk) {
    int idx = blockIdx.x * 256 + threadIdx.x;
    if (idx < NN) offs[idx] += cbase[idx >> 10];
    if (idx == 0) offs[NN] = cbase[nchunk - 1] + csum[nchunk - 1];
}

__global__ void k_scatter(const int* __restrict__ src, const int* __restrict__ dst,
                          const float* __restrict__ dist, int* __restrict__ cursor,
                          unsigned* __restrict__ epack) {
    int e = blockIdx.x * 256 + threadIdx.x;
    if (e >= EE) return;
    int d = dst[e];
    int pos = atomicAdd(&cursor[d], 1);
    int bin = (int)(dist[e] * 1024.0f + 0.5f);
    bin = (bin > TB - 1) ? (TB - 1) : bin;
    epack[pos] = ((unsigned)src[e] << 13) | (unsigned)bin;
}

// ---------- node GEMM: thread owns cols {lane, lane+64, lane+128, lane+192} of [src|dst] ----------
__global__ __launch_bounds__(256) void k_gemm(const float* __restrict__ x,
        const float* __restrict__ Ws, const float* __restrict__ bs,
        const float* __restrict__ Wd, const float* __restrict__ bd,
        unsigned* __restrict__ hs2p, unsigned* __restrict__ hd2p, int l) {
    __shared__ float4 Wc[64 * 64];  // [k][c] = (Ws[k][c], Ws[k][c+64], Wd[k][c], Wd[k][c+64])
    int tid = threadIdx.x;
    const float* WsL = Ws + l * 64 * 128;
    const float* WdL = Wd + l * 64 * 128;
    for (int idx = tid; idx < 64 * 64; idx += 256) {
        int k = idx >> 6, c = idx & 63;
        Wc[idx] = make_float4(WsL[k * 128 + c], WsL[k * 128 + 64 + c],
                              WdL[k * 128 + c], WdL[k * 128 + 64 + c]);
    }
    int w = tid >> 6, lane = tid & 63;
    float4 bias = make_float4(bs[l * 128 + lane], bs[l * 128 + 64 + lane],
                              bd[l * 128 + lane], bd[l * 128 + 64 + lane]);
    __syncthreads();
    for (int r0 = blockIdx.x * 16; r0 < NN; r0 += gridDim.x * 16) {
        int rb = r0 + w * 4;
        float4 acc[4];
        #pragma unroll
        for (int j = 0; j < 4; j++) acc[j] = bias;
        #pragma unroll
        for (int k4 = 0; k4 < 64; k4 += 4) {
            float4 xv[4];
            #pragma unroll
            for (int j = 0; j < 4; j++)
                xv[j] = *(const float4*)(x + (size_t)(rb + j) * 64 + k4);
            #pragma unroll
            for (int kk = 0; kk < 4; kk++) {
                float4 wv = Wc[(k4 + kk) * 64 + lane];
                #pragma unroll
                for (int j = 0; j < 4; j++) {
                    float xs = (kk == 0) ? xv[j].x : (kk == 1) ? xv[j].y : (kk == 2) ? xv[j].z : xv[j].w;
                    acc[j].x = fmaf(xs, wv.x, acc[j].x);
                    acc[j].y = fmaf(xs, wv.y, acc[j].y);
                    acc[j].z = fmaf(xs, wv.z, acc[j].z);
                    acc[j].w = fmaf(xs, wv.w, acc[j].w);
                }
            }
        }
        #pragma unroll
        for (int j = 0; j < 4; j++) {
            size_t p = (size_t)(rb + j) * 64 + lane;
            hs2p[p] = bfp(acc[j].x, acc[j].y);
            hd2p[p] = bfp(acc[j].z, acc[j].w);
        }
    }
}

// ---------- edge pass 1 (CSR): per-column sum/sumsq of m ----------
__global__ __launch_bounds__(256) void k_estats(const unsigned* __restrict__ hs2p,
        const unsigned* __restrict__ hd2p, const unsigned* __restrict__ Tpl,
        const unsigned* __restrict__ epack, const int* __restrict__ offs,
        float* __restrict__ stats) {
    int lane = threadIdx.x & 63, grp = threadIdx.x >> 6;
    float s1 = 0, q1 = 0, s2 = 0, q2 = 0;
    for (int v = blockIdx.x * 4 + grp; v < NN; v += gridDim.x * 4) {
        unsigned hd = hd2p[(size_t)v * 64 + lane];
        float hd1 = blo(hd), hd2 = bhi(hd);
        int e0 = offs[v], e1 = offs[v + 1];
        if (e0 >= e1) continue;
        unsigned ep = epack[e0];
        for (int e = e0; e < e1; e++) {
            unsigned epn = (e + 1 < e1) ? epack[e + 1] : 0u;
            unsigned hp = hs2p[(size_t)(ep >> 13) * 64 + lane];
            unsigned tp = Tpl[(size_t)(ep & 8191u) * 64 + lane];
            float m1 = hd1 + blo(hp) + blo(tp);
            float m2 = hd2 + bhi(hp) + bhi(tp);
            s1 += m1; q1 += m1 * m1; s2 += m2; q2 += m2 * m2;
            ep = epn;
        }
    }
    __shared__ float red[4][4][64];
    red[grp][0][lane] = s1; red[grp][1][lane] = s2;
    red[grp][2][lane] = q1; red[grp][3][lane] = q2;
    __syncthreads();
    if (threadIdx.x < 64) {
        float a0 = 0, a1 = 0, a2 = 0, a3 = 0;
        #pragma unroll
        for (int g = 0; g < 4; g++) {
            a0 += red[g][0][lane]; a1 += red[g][1][lane];
            a2 += red[g][2][lane]; a3 += red[g][3][lane];
        }
        atomicAdd(&stats[lane], a0);
        atomicAdd(&stats[64 + lane], a1);
        atomicAdd(&stats[128 + lane], a2);
        atomicAdd(&stats[192 + lane], a3);
    }
}

__global__ void k_bn1(float* __restrict__ stats, const float* __restrict__ g,
                      const float* __restrict__ b, int l) {
    int c = threadIdx.x;  // 128
    float mean = stats[c] * (1.0f / EE);
    float var = stats[128 + c] * (1.0f / EE) - mean * mean;
    float a = g[l * 128 + c] * rsqrtf(var + EPSV);
    stats[256 + c] = a;
    stats[384 + c] = b[l * 128 + c] - mean * a;
}

// ---------- edge pass 2 (CSR): normalize, gate, accumulate per node, no atomics ----------
__global__ __launch_bounds__(256) void k_eapply(const unsigned* __restrict__ hs2p,
        const unsigned* __restrict__ hd2p, const unsigned* __restrict__ Tpl,
        const unsigned* __restrict__ epack, const int* __restrict__ offs,
        const float* __restrict__ stats, float* __restrict__ hacc) {
    int lane = threadIdx.x & 63, grp = threadIdx.x >> 6;
    float a1 = stats[256 + lane], a2 = stats[320 + lane];
    float b1 = stats[384 + lane], b2 = stats[448 + lane];
    for (int v = blockIdx.x * 4 + grp; v < NN; v += gridDim.x * 4) {
        unsigned hd = hd2p[(size_t)v * 64 + lane];
        float hd1 = blo(hd), hd2 = bhi(hd);
        int e0 = offs[v], e1 = offs[v + 1];
        float accv = 0.0f;
        if (e0 < e1) {
            unsigned ep = epack[e0];
            for (int e = e0; e < e1; e++) {
                unsigned epn = (e + 1 < e1) ? epack[e + 1] : 0u;
                unsigned hp = hs2p[(size_t)(ep >> 13) * 64 + lane];
                unsigned tp = Tpl[(size_t)(ep & 8191u) * 64 + lane];
                float m1 = hd1 + blo(hp) + blo(tp);
                float m2 = hd2 + bhi(hp) + bhi(tp);
                float mn1 = fmaf(a1, m1, b1);
                float mn2 = fmaf(a2, m2, b2);
                float sig = 1.0f / (1.0f + __expf(-mn1));
                float sp = fmaxf(mn2, 0.0f) + log1pf(__expf(-fabsf(mn2)));
                accv = fmaf(sig, sp, accv);
                ep = epn;
            }
        }
        hacc[(size_t)v * 64 + lane] = accv;
    }
}

// ---------- node bn stats over hacc ----------
__global__ __launch_bounds__(256) void k_nstats(const float* __restrict__ hacc,
                                                float* __restrict__ nstats) {
    int lane = threadIdx.x & 63, grp = threadIdx.x >> 6;
    float s = 0, q = 0;
    for (int r = blockIdx.x * 4 + grp; r < NN; r += gridDim.x * 4) {
        float v = hacc[(size_t)r * 64 + lane];
        s += v; q += v * v;
    }
    __shared__ float red[4][2][64];
    red[grp][0][lane] = s; red[grp][1][lane] = q;
    __syncthreads();
    if (threadIdx.x < 64) {
        float a0 = 0, a1 = 0;
        #pragma unroll
        for (int g = 0; g < 4; g++) { a0 += red[g][0][lane]; a1 += red[g][1][lane]; }
        atomicAdd(&nstats[lane], a0);
        atomicAdd(&nstats[64 + lane], a1);
    }
}

__global__ void k_bn2(float* __restrict__ nstats, const float* __restrict__ g,
                      const float* __restrict__ b, int l) {
    int c = threadIdx.x;  // 64
    float mean = nstats[c] * (1.0f / NN);
    float var = nstats[64 + c] * (1.0f / NN) - mean * mean;
    float a = g[l * 64 + c] * rsqrtf(var + EPSV);
    nstats[128 + c] = a;
    nstats[192 + c] = b[l * 64 + c] - mean * a;
}

// ---------- x = softplus(x + bn(hacc)) ----------
__global__ void k_update(float* __restrict__ x, const float* __restrict__ hacc,
                         const float* __restrict__ nstats) {
    int i = blockIdx.x * 4 + (threadIdx.x >> 6);
    int c = threadIdx.x & 63;
    float v = x[i * 64 + c] + fmaf(nstats[128 + c], hacc[i * 64 + c], nstats[192 + c]);
    x[i * 64 + c] = fmaxf(v, 0.0f) + log1pf(__expf(-fabsf(v)));
}

// ---------- readout ----------
__global__ void k_pool(const float* __restrict__ x, const int* __restrict__ gid,
                       float* __restrict__ pooled, float* __restrict__ counts) {
    int i = blockIdx.x * 4 + (threadIdx.x >> 6);
    int c = threadIdx.x & 63;
    int g = gid[i];
    atomicAdd(&pooled[g * 64 + c], x[i * 64 + c]);
    if (c == 0) atomicAdd(&counts[g], 1.0f);
}

__global__ void k_out(const float* __restrict__ pooled, const float* __restrict__ counts,
                      float* __restrict__ out) {
    int g = blockIdx.x, c = threadIdx.x;
    out[g * 64 + c] = pooled[g * 64 + c] / fmaxf(counts[g], 1.0f);
}

extern "C" void kernel_launch(void* const* d_in, const int* in_sizes, int n_in,
                              void* d_out, int out_size, void* d_ws, size_t ws_size,
                              hipStream_t stream) {
    const int* atom_types   = (const int*)d_in[0];
    const float* distances  = (const float*)d_in[1];
    const int* src          = (const int*)d_in[2];
    const int* dst          = (const int*)d_in[3];
    const int* gid          = (const int*)d_in[4];
    const float* atom_table = (const float*)d_in[6];
    const float* W_embed    = (const float*)d_in[7];
    const float* b_embed    = (const float*)d_in[8];
    const float* W_src      = (const float*)d_in[9];
    const float* b_src      = (const float*)d_in[10];
    const float* W_dst      = (const float*)d_in[11];
    const float* b_dst      = (const float*)d_in[12];
    const float* W_edge     = (const float*)d_in[13];
    const float* b_edge     = (const float*)d_in[14];
    const float* g_msg      = (const float*)d_in[15];
    const float* beta_msg   = (const float*)d_in[16];
    const float* g_bn       = (const float*)d_in[17];
    const float* beta_bn    = (const float*)d_in[18];
    float* out = (float*)d_out;

    float* ws = (float*)d_ws;
    float* x        = ws;                             // N*64 f32
    float* hacc     = x + (size_t)NN * 64;            // N*64 f32
    unsigned* hs2p  = (unsigned*)(hacc + (size_t)NN * 64);   // N*64 u32
    unsigned* hd2p  = hs2p + (size_t)NN * 64;         // N*64 u32
    unsigned* Tp    = hd2p + (size_t)NN * 64;         // 3*TB*64 u32
    unsigned* epack = Tp + (size_t)3 * TB * 64;       // EE u32
    float* emb      = (float*)(epack + (size_t)EE);   // 95*64
    float* stats    = emb + 95 * 64;                  // 512
    float* nstats   = stats + 512;                    // 256
    float* pooled   = nstats + 256;                   // G*64
    float* counts   = pooled + GG * 64;               // G
    int* deg        = (int*)(counts + GG);            // N
    int* offs       = deg + NN;                       // N+1
    int* cursor     = offs + NN + 1;                  // N
    int* csum       = cursor + NN;                    // 128
    int* cbase      = csum + 128;                     // 130

    const int NCH = (NN + 1023) / 1024;  // 98

    // featurization + embedding
    k_emb<<<95, 64, 0, stream>>>(atom_table, W_embed, b_embed, emb);
    k_table<<<dim3(TB, 3), 64, 0, stream>>>(W_edge, b_edge, Tp);
    k_ninit<<<NN / 4, 256, 0, stream>>>(atom_types, emb, x);

    // CSR build (once per call; dst fixed across layers)
    hipMemsetAsync(deg, 0, NN * sizeof(int), stream);
    k_hist<<<(EE + 255) / 256, 256, 0, stream>>>(dst, deg);
    k_scanA<<<NCH, 1024, 0, stream>>>(deg, offs, csum);
    k_scanB<<<1, 128, 0, stream>>>(csum, cbase, NCH);
    k_scanC<<<(NN + 255) / 256, 256, 0, stream>>>(offs, cbase, csum, NCH);
    hipMemcpyAsync(cursor, offs, NN * sizeof(int), hipMemcpyDeviceToDevice, stream);
    k_scatter<<<(EE + 255) / 256, 256, 0, stream>>>(src, dst, distances, cursor, epack);

    for (int l = 0; l < 3; l++) {
        hipMemsetAsync(stats, 0, 768 * sizeof(float), stream);
        k_gemm<<<512, 256, 0, stream>>>(x, W_src, b_src, W_dst, b_dst, hs2p, hd2p, l);
        const unsigned* Tpl = Tp + (size_t)l * TB * 64;
        k_estats<<<4096, 256, 0, stream>>>(hs2p, hd2p, Tpl, epack, offs, stats);
        k_bn1<<<1, 128, 0, stream>>>(stats, g_msg, beta_msg, l);
        k_eapply<<<4096, 256, 0, stream>>>(hs2p, hd2p, Tpl, epack, offs, stats, hacc);
        k_nstats<<<2048, 256, 0, stream>>>(hacc, nstats);
        k_bn2<<<1, 64, 0, stream>>>(nstats, g_bn, beta_bn, l);
        k_update<<<NN / 4, 256, 0, stream>>>(x, hacc, nstats);
    }

    hipMemsetAsync(pooled, 0, (GG * 64 + GG) * sizeof(float), stream);
    k_pool<<<NN / 4, 256, 0, stream>>>(x, gid, pooled, counts);
    k_out<<<GG, 64, 0, stream>>>(pooled, counts, out);
}

// Round 3
// 3194.610 us; speedup vs baseline: 1.3066x; 1.1038x over previous
//
#include <hip/hip_runtime.h>
#include <math.h>

#define NN 100000
#define EE 1600000
#define GG 256
#define TB 8192
#define EPSV 1e-5f

__device__ __forceinline__ float blo(unsigned u) { return __uint_as_float(u << 16); }
__device__ __forceinline__ float bhi(unsigned u) { return __uint_as_float(u & 0xffff0000u); }
__device__ __forceinline__ unsigned bfp(float a, float b) {  // pack (lo=a, hi=b) bf16 RNE
    unsigned ua = __float_as_uint(a), ub = __float_as_uint(b);
    ua += 0x7fffu + ((ua >> 16) & 1u);
    ub += 0x7fffu + ((ub >> 16) & 1u);
    return (ua >> 16) | (ub & 0xffff0000u);
}

// ---------- embedding table: emb[95][64] = atom_table @ W_embed + b ----------
__global__ void k_emb(const float* __restrict__ at, const float* __restrict__ We,
                      const float* __restrict__ be, float* __restrict__ emb) {
    int t = blockIdx.x, c = threadIdx.x;
    float acc = be[c];
    const float* ar = at + t * 200;
    for (int k = 0; k < 200; k++) acc = fmaf(ar[k], We[k * 64 + c], acc);
    emb[t * 64 + c] = acc;
}

// ---------- x[n] = emb[type[n]] ----------
__global__ void k_ninit(const int* __restrict__ types, const float* __restrict__ emb,
                        float* __restrict__ x) {
    int i = blockIdx.x * 4 + (threadIdx.x >> 6);
    int c = threadIdx.x & 63;
    x[i * 64 + c] = emb[types[i] * 64 + c];
}

// ---------- distance table (nearest bin), bf16 pair packed ----------
__global__ void k_table(const float* __restrict__ We, const float* __restrict__ be,
                        unsigned* __restrict__ Tp) {
    int i = blockIdx.x, l = blockIdx.y, c = threadIdx.x;  // 64 threads
    __shared__ float rbf[40];
    float d = i * (1.0f / 1024.0f);  // bin center, matches bin = round(d*1024)
    if (c < 40) { float u = d - c * (8.0f / 39.0f); rbf[c] = expf(-4.875f * u * u); }
    __syncthreads();
    const float* W = We + l * 40 * 128;
    float a1 = be[l * 128 + c], a2 = be[l * 128 + 64 + c];
    for (int k = 0; k < 40; k++) {
        a1 = fmaf(rbf[k], W[k * 128 + c], a1);
        a2 = fmaf(rbf[k], W[k * 128 + 64 + c], a2);
    }
    Tp[((size_t)l * TB + i) * 64 + c] = bfp(a1, a2);
}

// ---------- CSR build ----------
__global__ void k_hist(const int* __restrict__ dst, int* __restrict__ deg) {
    int e = blockIdx.x * 256 + threadIdx.x;
    if (e < EE) atomicAdd(&deg[dst[e]], 1);
}

__global__ __launch_bounds__(1024) void k_scanA(const int* __restrict__ deg,
                                                int* __restrict__ offs, int* __restrict__ csum) {
    __shared__ int tmp[1024];
    int idx = blockIdx.x * 1024 + threadIdx.x;
    int v = (idx < NN) ? deg[idx] : 0;
    tmp[threadIdx.x] = v;
    __syncthreads();
    for (int off = 1; off < 1024; off <<= 1) {
        int t = (threadIdx.x >= off) ? tmp[threadIdx.x - off] : 0;
        __syncthreads();
        tmp[threadIdx.x] += t;
        __syncthreads();
    }
    if (idx < NN) offs[idx] = tmp[threadIdx.x] - v;
    if (threadIdx.x == 1023) csum[blockIdx.x] = tmp[1023];
}

__global__ __launch_bounds__(128) void k_scanB(int* __restrict__ csum, int* __restrict__ cbase,
                                               int nchunk) {
    __shared__ int tmp[128];
    int v = (threadIdx.x < nchunk) ? csum[threadIdx.x] : 0;
    tmp[threadIdx.x] = v;
    __syncthreads();
    for (int off = 1; off < 128; off <<= 1) {
        int t = (threadIdx.x >= off) ? tmp[threadIdx.x - off] : 0;
        __syncthreads();
        tmp[threadIdx.x] += t;
        __syncthreads();
    }
    cbase[threadIdx.x] = tmp[threadIdx.x] - v;
}

__global__ void k_scanC(int* __restrict__ offs, const int* __restrict__ cbase,
                        const int* __restrict__ csum, int nchunk) {
    int idx = blockIdx.x * 256 + threadIdx.x;
    if (idx < NN) offs[idx] += cbase[idx >> 10];
    if (idx == 0) offs[NN] = cbase[nchunk - 1] + csum[nchunk - 1];
}

__global__ void k_scatter(const int* __restrict__ src, const int* __restrict__ dst,
                          const float* __restrict__ dist, int* __restrict__ cursor,
                          unsigned* __restrict__ epack) {
    int e = blockIdx.x * 256 + threadIdx.x;
    if (e >= EE) return;
    int d = dst[e];
    int pos = atomicAdd(&cursor[d], 1);
    int bin = (int)(dist[e] * 1024.0f + 0.5f);
    bin = (bin > TB - 1) ? (TB - 1) : bin;
    epack[pos] = ((unsigned)src[e] << 13) | (unsigned)bin;
}

// ---------- node GEMM ----------
__global__ __launch_bounds__(256) void k_gemm(const float* __restrict__ x,
        const float* __restrict__ Ws, const float* __restrict__ bs,
        const float* __restrict__ Wd, const float* __restrict__ bd,
        unsigned* __restrict__ hs2p, unsigned* __restrict__ hd2p, int l) {
    __shared__ float4 Wc[64 * 64];  // [k][c] = (Ws[k][c], Ws[k][c+64], Wd[k][c], Wd[k][c+64])
    int tid = threadIdx.x;
    const float* WsL = Ws + l * 64 * 128;
    const float* WdL = Wd + l * 64 * 128;
    for (int idx = tid; idx < 64 * 64; idx += 256) {
        int k = idx >> 6, c = idx & 63;
        Wc[idx] = make_float4(WsL[k * 128 + c], WsL[k * 128 + 64 + c],
                              WdL[k * 128 + c], WdL[k * 128 + 64 + c]);
    }
    int w = tid >> 6, lane = tid & 63;
    float4 bias = make_float4(bs[l * 128 + lane], bs[l * 128 + 64 + lane],
                              bd[l * 128 + lane], bd[l * 128 + 64 + lane]);
    __syncthreads();
    for (int r0 = blockIdx.x * 16; r0 < NN; r0 += gridDim.x * 16) {
        int rb = r0 + w * 4;
        float4 acc[4];
        #pragma unroll
        for (int j = 0; j < 4; j++) acc[j] = bias;
        #pragma unroll
        for (int k4 = 0; k4 < 64; k4 += 4) {
            float4 xv[4];
            #pragma unroll
            for (int j = 0; j < 4; j++)
                xv[j] = *(const float4*)(x + (size_t)(rb + j) * 64 + k4);
            #pragma unroll
            for (int kk = 0; kk < 4; kk++) {
                float4 wv = Wc[(k4 + kk) * 64 + lane];
                #pragma unroll
                for (int j = 0; j < 4; j++) {
                    float xs = (kk == 0) ? xv[j].x : (kk == 1) ? xv[j].y : (kk == 2) ? xv[j].z : xv[j].w;
                    acc[j].x = fmaf(xs, wv.x, acc[j].x);
                    acc[j].y = fmaf(xs, wv.y, acc[j].y);
                    acc[j].z = fmaf(xs, wv.z, acc[j].z);
                    acc[j].w = fmaf(xs, wv.w, acc[j].w);
                }
            }
        }
        #pragma unroll
        for (int j = 0; j < 4; j++) {
            size_t p = (size_t)(rb + j) * 64 + lane;
            hs2p[p] = bfp(acc[j].x, acc[j].y);
            hd2p[p] = bfp(acc[j].z, acc[j].w);
        }
    }
}

// ---------- edge pass 1 (CSR, unroll-8): per-column sum/sumsq of m ----------
__global__ __launch_bounds__(256) void k_estats(const unsigned* __restrict__ hs2p,
        const unsigned* __restrict__ hd2p, const unsigned* __restrict__ Tpl,
        const unsigned* __restrict__ epack, const int* __restrict__ offs,
        float* __restrict__ stats) {
    int lane = threadIdx.x & 63, grp = threadIdx.x >> 6;
    float s1 = 0, q1 = 0, s2 = 0, q2 = 0;
    for (int v = blockIdx.x * 4 + grp; v < NN; v += gridDim.x * 4) {
        unsigned hd = hd2p[(size_t)v * 64 + lane];
        float hd1 = blo(hd), hd2v = bhi(hd);
        int e0 = offs[v], e1 = offs[v + 1];
        int e = e0;
        for (; e + 8 <= e1; e += 8) {
            unsigned epv[8], hp[8], tp[8];
            #pragma unroll
            for (int j = 0; j < 8; j++) epv[j] = epack[e + j];
            #pragma unroll
            for (int j = 0; j < 8; j++) {
                hp[j] = hs2p[(size_t)(epv[j] >> 13) * 64 + lane];
                tp[j] = Tpl[(size_t)(epv[j] & 8191u) * 64 + lane];
            }
            #pragma unroll
            for (int j = 0; j < 8; j++) {
                float m1 = hd1 + blo(hp[j]) + blo(tp[j]);
                float m2 = hd2v + bhi(hp[j]) + bhi(tp[j]);
                s1 += m1; q1 += m1 * m1; s2 += m2; q2 += m2 * m2;
            }
        }
        for (; e < e1; e++) {
            unsigned ep = epack[e];
            unsigned hp = hs2p[(size_t)(ep >> 13) * 64 + lane];
            unsigned tp = Tpl[(size_t)(ep & 8191u) * 64 + lane];
            float m1 = hd1 + blo(hp) + blo(tp);
            float m2 = hd2v + bhi(hp) + bhi(tp);
            s1 += m1; q1 += m1 * m1; s2 += m2; q2 += m2 * m2;
        }
    }
    __shared__ float red[4][4][64];
    red[grp][0][lane] = s1; red[grp][1][lane] = s2;
    red[grp][2][lane] = q1; red[grp][3][lane] = q2;
    __syncthreads();
    if (threadIdx.x < 64) {
        float a0 = 0, a1 = 0, a2 = 0, a3 = 0;
        #pragma unroll
        for (int g = 0; g < 4; g++) {
            a0 += red[g][0][lane]; a1 += red[g][1][lane];
            a2 += red[g][2][lane]; a3 += red[g][3][lane];
        }
        atomicAdd(&stats[lane], a0);
        atomicAdd(&stats[64 + lane], a1);
        atomicAdd(&stats[128 + lane], a2);
        atomicAdd(&stats[192 + lane], a3);
    }
}

__global__ void k_bn1(float* __restrict__ stats, const float* __restrict__ g,
                      const float* __restrict__ b, int l) {
    int c = threadIdx.x;  // 128
    float mean = stats[c] * (1.0f / EE);
    float var = stats[128 + c] * (1.0f / EE) - mean * mean;
    float a = g[l * 128 + c] * rsqrtf(var + EPSV);
    stats[256 + c] = a;
    stats[384 + c] = b[l * 128 + c] - mean * a;
}

// ---------- edge pass 2 (CSR, unroll-8): gate + accumulate + fused node-bn stats ----------
__global__ __launch_bounds__(256) void k_eapply(const unsigned* __restrict__ hs2p,
        const unsigned* __restrict__ hd2p, const unsigned* __restrict__ Tpl,
        const unsigned* __restrict__ epack, const int* __restrict__ offs,
        const float* __restrict__ stats, float* __restrict__ hacc,
        float* __restrict__ nstats) {
    int lane = threadIdx.x & 63, grp = threadIdx.x >> 6;
    float a1 = stats[256 + lane], a2 = stats[320 + lane];
    float b1 = stats[384 + lane], b2 = stats[448 + lane];
    float ns = 0, nq = 0;
    for (int v = blockIdx.x * 4 + grp; v < NN; v += gridDim.x * 4) {
        unsigned hd = hd2p[(size_t)v * 64 + lane];
        float hd1 = blo(hd), hd2v = bhi(hd);
        int e0 = offs[v], e1 = offs[v + 1];
        float accv = 0.0f;
        int e = e0;
        for (; e + 8 <= e1; e += 8) {
            unsigned epv[8], hp[8], tp[8];
            #pragma unroll
            for (int j = 0; j < 8; j++) epv[j] = epack[e + j];
            #pragma unroll
            for (int j = 0; j < 8; j++) {
                hp[j] = hs2p[(size_t)(epv[j] >> 13) * 64 + lane];
                tp[j] = Tpl[(size_t)(epv[j] & 8191u) * 64 + lane];
            }
            #pragma unroll
            for (int j = 0; j < 8; j++) {
                float m1 = hd1 + blo(hp[j]) + blo(tp[j]);
                float m2 = hd2v + bhi(hp[j]) + bhi(tp[j]);
                float mn1 = fmaf(a1, m1, b1);
                float mn2 = fmaf(a2, m2, b2);
                float sig = 1.0f / (1.0f + __expf(-mn1));
                float sp = fmaxf(mn2, 0.0f) + log1pf(__expf(-fabsf(mn2)));
                accv = fmaf(sig, sp, accv);
            }
        }
        for (; e < e1; e++) {
            unsigned ep = epack[e];
            unsigned hp = hs2p[(size_t)(ep >> 13) * 64 + lane];
            unsigned tp = Tpl[(size_t)(ep & 8191u) * 64 + lane];
            float m1 = hd1 + blo(hp) + blo(tp);
            float m2 = hd2v + bhi(hp) + bhi(tp);
            float mn1 = fmaf(a1, m1, b1);
            float mn2 = fmaf(a2, m2, b2);
            float sig = 1.0f / (1.0f + __expf(-mn1));
            float sp = fmaxf(mn2, 0.0f) + log1pf(__expf(-fabsf(mn2)));
            accv = fmaf(sig, sp, accv);
        }
        hacc[(size_t)v * 64 + lane] = accv;
        ns += accv; nq += accv * accv;
    }
    __shared__ float red[4][2][64];
    red[grp][0][lane] = ns; red[grp][1][lane] = nq;
    __syncthreads();
    if (threadIdx.x < 64) {
        float a0 = 0, a1s = 0;
        #pragma unroll
        for (int g = 0; g < 4; g++) { a0 += red[g][0][lane]; a1s += red[g][1][lane]; }
        atomicAdd(&nstats[lane], a0);
        atomicAdd(&nstats[64 + lane], a1s);
    }
}

__global__ void k_bn2(float* __restrict__ nstats, const float* __restrict__ g,
                      const float* __restrict__ b, int l) {
    int c = threadIdx.x;  // 64
    float mean = nstats[c] * (1.0f / NN);
    float var = nstats[64 + c] * (1.0f / NN) - mean * mean;
    float a = g[l * 64 + c] * rsqrtf(var + EPSV);
    nstats[128 + c] = a;
    nstats[192 + c] = b[l * 64 + c] - mean * a;
}

// ---------- x = softplus(x + bn(hacc)) ----------
__global__ void k_update(float* __restrict__ x, const float* __restrict__ hacc,
                         const float* __restrict__ nstats) {
    int i = blockIdx.x * 4 + (threadIdx.x >> 6);
    int c = threadIdx.x & 63;
    float v = x[i * 64 + c] + fmaf(nstats[128 + c], hacc[i * 64 + c], nstats[192 + c]);
    x[i * 64 + c] = fmaxf(v, 0.0f) + log1pf(__expf(-fabsf(v)));
}

// ---------- readout ----------
__global__ void k_pool(const float* __restrict__ x, const int* __restrict__ gid,
                       float* __restrict__ pooled, float* __restrict__ counts) {
    int i = blockIdx.x * 4 + (threadIdx.x >> 6);
    int c = threadIdx.x & 63;
    int g = gid[i];
    atomicAdd(&pooled[g * 64 + c], x[i * 64 + c]);
    if (c == 0) atomicAdd(&counts[g], 1.0f);
}

__global__ void k_out(const float* __restrict__ pooled, const float* __restrict__ counts,
                      float* __restrict__ out) {
    int g = blockIdx.x, c = threadIdx.x;
    out[g * 64 + c] = pooled[g * 64 + c] / fmaxf(counts[g], 1.0f);
}

extern "C" void kernel_launch(void* const* d_in, const int* in_sizes, int n_in,
                              void* d_out, int out_size, void* d_ws, size_t ws_size,
                              hipStream_t stream) {
    const int* atom_types   = (const int*)d_in[0];
    const float* distances  = (const float*)d_in[1];
    const int* src          = (const int*)d_in[2];
    const int* dst          = (const int*)d_in[3];
    const int* gid          = (const int*)d_in[4];
    const float* atom_table = (const float*)d_in[6];
    const float* W_embed    = (const float*)d_in[7];
    const float* b_embed    = (const float*)d_in[8];
    const float* W_src      = (const float*)d_in[9];
    const float* b_src      = (const float*)d_in[10];
    const float* W_dst      = (const float*)d_in[11];
    const float* b_dst      = (const float*)d_in[12];
    const float* W_edge     = (const float*)d_in[13];
    const float* b_edge     = (const float*)d_in[14];
    const float* g_msg      = (const float*)d_in[15];
    const float* beta_msg   = (const float*)d_in[16];
    const float* g_bn       = (const float*)d_in[17];
    const float* beta_bn    = (const float*)d_in[18];
    float* out = (float*)d_out;

    float* ws = (float*)d_ws;
    float* x        = ws;                             // N*64 f32
    float* hacc     = x + (size_t)NN * 64;            // N*64 f32
    unsigned* hs2p  = (unsigned*)(hacc + (size_t)NN * 64);   // N*64 u32
    unsigned* hd2p  = hs2p + (size_t)NN * 64;         // N*64 u32
    unsigned* Tp    = hd2p + (size_t)NN * 64;         // 3*TB*64 u32
    unsigned* epack = Tp + (size_t)3 * TB * 64;       // EE u32
    float* emb      = (float*)(epack + (size_t)EE);   // 95*64
    float* stats    = emb + 95 * 64;                  // 512
    float* nstats   = stats + 512;                    // 256
    float* pooled   = nstats + 256;                   // G*64
    float* counts   = pooled + GG * 64;               // G
    int* deg        = (int*)(counts + GG);            // N
    int* offs       = deg + NN;                       // N+1
    int* cursor     = offs + NN + 1;                  // N
    int* csum       = cursor + NN;                    // 128
    int* cbase      = csum + 128;                     // 130

    const int NCH = (NN + 1023) / 1024;  // 98

    k_emb<<<95, 64, 0, stream>>>(atom_table, W_embed, b_embed, emb);
    k_table<<<dim3(TB, 3), 64, 0, stream>>>(W_edge, b_edge, Tp);
    k_ninit<<<NN / 4, 256, 0, stream>>>(atom_types, emb, x);

    hipMemsetAsync(deg, 0, NN * sizeof(int), stream);
    k_hist<<<(EE + 255) / 256, 256, 0, stream>>>(dst, deg);
    k_scanA<<<NCH, 1024, 0, stream>>>(deg, offs, csum);
    k_scanB<<<1, 128, 0, stream>>>(csum, cbase, NCH);
    k_scanC<<<(NN + 255) / 256, 256, 0, stream>>>(offs, cbase, csum, NCH);
    hipMemcpyAsync(cursor, offs, NN * sizeof(int), hipMemcpyDeviceToDevice, stream);
    k_scatter<<<(EE + 255) / 256, 256, 0, stream>>>(src, dst, distances, cursor, epack);

    for (int l = 0; l < 3; l++) {
        hipMemsetAsync(stats, 0, (768 + 256) * sizeof(float), stream);
        k_gemm<<<512, 256, 0, stream>>>(x, W_src, b_src, W_dst, b_dst, hs2p, hd2p, l);
        const unsigned* Tpl = Tp + (size_t)l * TB * 64;
        k_estats<<<4096, 256, 0, stream>>>(hs2p, hd2p, Tpl, epack, offs, stats);
        k_bn1<<<1, 128, 0, stream>>>(stats, g_msg, beta_msg, l);
        k_eapply<<<4096, 256, 0, stream>>>(hs2p, hd2p, Tpl, epack, offs, stats, hacc, nstats);
        k_bn2<<<1, 64, 0, stream>>>(nstats, g_bn, beta_bn, l);
        k_update<<<NN / 4, 256, 0, stream>>>(x, hacc, nstats);
    }

    hipMemsetAsync(pooled, 0, (GG * 64 + GG) * sizeof(float), stream);
    k_pool<<<NN / 4, 256, 0, stream>>>(x, gid, pooled, counts);
    k_out<<<GG, 64, 0, stream>>>(pooled, counts, out);
}

// Round 4
// 2328.461 us; speedup vs baseline: 1.7926x; 1.3720x over previous
//
#include <hip/hip_runtime.h>
#include <math.h>

#define NN 100000
#define EE 1600000
#define GG 256
#define TB 8192
#define EPSV 1e-5f

__device__ __forceinline__ float blo(unsigned u) { return __uint_as_float(u << 16); }
__device__ __forceinline__ float bhi(unsigned u) { return __uint_as_float(u & 0xffff0000u); }
__device__ __forceinline__ unsigned bfp(float a, float b) {  // pack (lo=a, hi=b) bf16 RNE
    unsigned ua = __float_as_uint(a), ub = __float_as_uint(b);
    ua += 0x7fffu + ((ua >> 16) & 1u);
    ub += 0x7fffu + ((ub >> 16) & 1u);
    return (ua >> 16) | (ub & 0xffff0000u);
}
__device__ __forceinline__ float fast_sig(float x) {
    return __builtin_amdgcn_rcpf(1.0f + __expf(-x));
}
__device__ __forceinline__ float fast_sp(float x) {
    return fmaxf(x, 0.0f) + __logf(1.0f + __expf(-fabsf(x)));
}

// ---------- embedding table: emb[95][64] = atom_table @ W_embed + b ----------
__global__ void k_emb(const float* __restrict__ at, const float* __restrict__ We,
                      const float* __restrict__ be, float* __restrict__ emb) {
    int t = blockIdx.x, c = threadIdx.x;
    float acc = be[c];
    const float* ar = at + t * 200;
    for (int k = 0; k < 200; k++) acc = fmaf(ar[k], We[k * 64 + c], acc);
    emb[t * 64 + c] = acc;
}

// ---------- x[n] = emb[type[n]] ----------
__global__ void k_ninit(const int* __restrict__ types, const float* __restrict__ emb,
                        float* __restrict__ x) {
    int i = blockIdx.x * 4 + (threadIdx.x >> 6);
    int c = threadIdx.x & 63;
    x[i * 64 + c] = emb[types[i] * 64 + c];
}

// ---------- distance table (nearest bin), bf16 pair packed ----------
__global__ void k_table(const float* __restrict__ We, const float* __restrict__ be,
                        unsigned* __restrict__ Tp) {
    int i = blockIdx.x, l = blockIdx.y, c = threadIdx.x;  // 64 threads
    __shared__ float rbf[40];
    float d = i * (1.0f / 1024.0f);  // bin center, matches bin = round(d*1024)
    if (c < 40) { float u = d - c * (8.0f / 39.0f); rbf[c] = expf(-4.875f * u * u); }
    __syncthreads();
    const float* W = We + l * 40 * 128;
    float a1 = be[l * 128 + c], a2 = be[l * 128 + 64 + c];
    for (int k = 0; k < 40; k++) {
        a1 = fmaf(rbf[k], W[k * 128 + c], a1);
        a2 = fmaf(rbf[k], W[k * 128 + 64 + c], a2);
    }
    Tp[((size_t)l * TB + i) * 64 + c] = bfp(a1, a2);
}

// ---------- CSR build ----------
__global__ void k_hist(const int* __restrict__ dst, int* __restrict__ deg) {
    int e = blockIdx.x * 256 + threadIdx.x;
    if (e < EE) atomicAdd(&deg[dst[e]], 1);
}

__global__ __launch_bounds__(1024) void k_scanA(const int* __restrict__ deg,
                                                int* __restrict__ offs, int* __restrict__ csum) {
    __shared__ int tmp[1024];
    int idx = blockIdx.x * 1024 + threadIdx.x;
    int v = (idx < NN) ? deg[idx] : 0;
    tmp[threadIdx.x] = v;
    __syncthreads();
    for (int off = 1; off < 1024; off <<= 1) {
        int t = (threadIdx.x >= off) ? tmp[threadIdx.x - off] : 0;
        __syncthreads();
        tmp[threadIdx.x] += t;
        __syncthreads();
    }
    if (idx < NN) offs[idx] = tmp[threadIdx.x] - v;
    if (threadIdx.x == 1023) csum[blockIdx.x] = tmp[1023];
}

__global__ __launch_bounds__(128) void k_scanB(int* __restrict__ csum, int* __restrict__ cbase,
                                               int nchunk) {
    __shared__ int tmp[128];
    int v = (threadIdx.x < nchunk) ? csum[threadIdx.x] : 0;
    tmp[threadIdx.x] = v;
    __syncthreads();
    for (int off = 1; off < 128; off <<= 1) {
        int t = (threadIdx.x >= off) ? tmp[threadIdx.x - off] : 0;
        __syncthreads();
        tmp[threadIdx.x] += t;
        __syncthreads();
    }
    cbase[threadIdx.x] = tmp[threadIdx.x] - v;
}

__global__ void k_scanC(int* __restrict__ offs, const int* __restrict__ cbase,
                        const int* __restrict__ csum, int nchunk) {
    int idx = blockIdx.x * 256 + threadIdx.x;
    if (idx < NN) offs[idx] += cbase[idx >> 10];
    if (idx == 0) offs[NN] = cbase[nchunk - 1] + csum[nchunk - 1];
}

__global__ void k_scatter(const int* __restrict__ src, const int* __restrict__ dst,
                          const float* __restrict__ dist, int* __restrict__ cursor,
                          unsigned* __restrict__ epack) {
    int e = blockIdx.x * 256 + threadIdx.x;
    if (e >= EE) return;
    int d = dst[e];
    int pos = atomicAdd(&cursor[d], 1);
    int bin = (int)(dist[e] * 1024.0f + 0.5f);
    bin = (bin > TB - 1) ? (TB - 1) : bin;
    epack[pos] = ((unsigned)src[e] << 13) | (unsigned)bin;
}

// ---------- node GEMM ----------
__global__ __launch_bounds__(256) void k_gemm(const float* __restrict__ x,
        const float* __restrict__ Ws, const float* __restrict__ bs,
        const float* __restrict__ Wd, const float* __restrict__ bd,
        unsigned* __restrict__ hs2p, unsigned* __restrict__ hd2p, int l) {
    __shared__ float4 Wc[64 * 64];  // [k][c] = (Ws[k][c], Ws[k][c+64], Wd[k][c], Wd[k][c+64])
    int tid = threadIdx.x;
    const float* WsL = Ws + l * 64 * 128;
    const float* WdL = Wd + l * 64 * 128;
    for (int idx = tid; idx < 64 * 64; idx += 256) {
        int k = idx >> 6, c = idx & 63;
        Wc[idx] = make_float4(WsL[k * 128 + c], WsL[k * 128 + 64 + c],
                              WdL[k * 128 + c], WdL[k * 128 + 64 + c]);
    }
    int w = tid >> 6, lane = tid & 63;
    float4 bias = make_float4(bs[l * 128 + lane], bs[l * 128 + 64 + lane],
                              bd[l * 128 + lane], bd[l * 128 + 64 + lane]);
    __syncthreads();
    for (int r0 = blockIdx.x * 16; r0 < NN; r0 += gridDim.x * 16) {
        int rb = r0 + w * 4;
        float4 acc[4];
        #pragma unroll
        for (int j = 0; j < 4; j++) acc[j] = bias;
        #pragma unroll
        for (int k4 = 0; k4 < 64; k4 += 4) {
            float4 xv[4];
            #pragma unroll
            for (int j = 0; j < 4; j++)
                xv[j] = *(const float4*)(x + (size_t)(rb + j) * 64 + k4);
            #pragma unroll
            for (int kk = 0; kk < 4; kk++) {
                float4 wv = Wc[(k4 + kk) * 64 + lane];
                #pragma unroll
                for (int j = 0; j < 4; j++) {
                    float xs = (kk == 0) ? xv[j].x : (kk == 1) ? xv[j].y : (kk == 2) ? xv[j].z : xv[j].w;
                    acc[j].x = fmaf(xs, wv.x, acc[j].x);
                    acc[j].y = fmaf(xs, wv.y, acc[j].y);
                    acc[j].z = fmaf(xs, wv.z, acc[j].z);
                    acc[j].w = fmaf(xs, wv.w, acc[j].w);
                }
            }
        }
        #pragma unroll
        for (int j = 0; j < 4; j++) {
            size_t p = (size_t)(rb + j) * 64 + lane;
            hs2p[p] = bfp(acc[j].x, acc[j].y);
            hd2p[p] = bfp(acc[j].z, acc[j].w);
        }
    }
}

// ---------- edge pass 1: quad-edge dwordx4 gathers; per-column sum/sumsq of m ----------
__global__ __launch_bounds__(256) void k_estats(const unsigned* __restrict__ hs2p,
        const unsigned* __restrict__ hd2p, const unsigned* __restrict__ Tpl,
        const unsigned* __restrict__ epack, const int* __restrict__ offs,
        float* __restrict__ stats) {
    int lane = threadIdx.x & 63, grp = threadIdx.x >> 6;
    int q = (lane >> 4) & 3, t = lane & 15;
    float s1[4] = {0, 0, 0, 0}, q1[4] = {0, 0, 0, 0};
    float s2[4] = {0, 0, 0, 0}, q2[4] = {0, 0, 0, 0};
    for (int v = blockIdx.x * 4 + grp; v < NN; v += gridDim.x * 4) {
        uint4 hdv = *(const uint4*)(hd2p + (size_t)v * 64 + t * 4);
        unsigned hda[4] = {hdv.x, hdv.y, hdv.z, hdv.w};
        float hd1[4], hd2c[4];
        #pragma unroll
        for (int k = 0; k < 4; k++) { hd1[k] = blo(hda[k]); hd2c[k] = bhi(hda[k]); }
        int e0 = offs[v], e1 = offs[v + 1];
        for (int e = e0; e < e1; e += 8) {
            int eA = e + q, eB = eA + 4;
            unsigned epA = epack[(eA < e1) ? eA : (e1 - 1)];
            unsigned epB = epack[(eB < e1) ? eB : (e1 - 1)];
            uint4 hsA = *(const uint4*)(hs2p + (size_t)(epA >> 13) * 64 + t * 4);
            uint4 tA  = *(const uint4*)(Tpl + (size_t)(epA & 8191u) * 64 + t * 4);
            uint4 hsB = *(const uint4*)(hs2p + (size_t)(epB >> 13) * 64 + t * 4);
            uint4 tB  = *(const uint4*)(Tpl + (size_t)(epB & 8191u) * 64 + t * 4);
            float wA = (eA < e1) ? 1.0f : 0.0f;
            float wB = (eB < e1) ? 1.0f : 0.0f;
            unsigned ha[4] = {hsA.x, hsA.y, hsA.z, hsA.w};
            unsigned ta[4] = {tA.x, tA.y, tA.z, tA.w};
            unsigned hb[4] = {hsB.x, hsB.y, hsB.z, hsB.w};
            unsigned tb[4] = {tB.x, tB.y, tB.z, tB.w};
            #pragma unroll
            for (int k = 0; k < 4; k++) {
                float m1 = hd1[k] + blo(ha[k]) + blo(ta[k]);
                float m2 = hd2c[k] + bhi(ha[k]) + bhi(ta[k]);
                s1[k] = fmaf(wA, m1, s1[k]); q1[k] = fmaf(wA * m1, m1, q1[k]);
                s2[k] = fmaf(wA, m2, s2[k]); q2[k] = fmaf(wA * m2, m2, q2[k]);
                float n1 = hd1[k] + blo(hb[k]) + blo(tb[k]);
                float n2 = hd2c[k] + bhi(hb[k]) + bhi(tb[k]);
                s1[k] = fmaf(wB, n1, s1[k]); q1[k] = fmaf(wB * n1, n1, q1[k]);
                s2[k] = fmaf(wB, n2, s2[k]); q2[k] = fmaf(wB * n2, n2, q2[k]);
            }
        }
    }
    // reduce over q (lanes t, t+16, t+32, t+48)
    #pragma unroll
    for (int k = 0; k < 4; k++) {
        s1[k] += __shfl_down(s1[k], 32); s1[k] += __shfl_down(s1[k], 16);
        s2[k] += __shfl_down(s2[k], 32); s2[k] += __shfl_down(s2[k], 16);
        q1[k] += __shfl_down(q1[k], 32); q1[k] += __shfl_down(q1[k], 16);
        q2[k] += __shfl_down(q2[k], 32); q2[k] += __shfl_down(q2[k], 16);
    }
    __shared__ float red[4][4][64];
    if (lane < 16) {
        #pragma unroll
        for (int k = 0; k < 4; k++) {
            red[grp][0][t * 4 + k] = s1[k];
            red[grp][1][t * 4 + k] = s2[k];
            red[grp][2][t * 4 + k] = q1[k];
            red[grp][3][t * 4 + k] = q2[k];
        }
    }
    __syncthreads();
    if (threadIdx.x < 64) {
        int c = threadIdx.x;
        float a0 = 0, a1 = 0, a2 = 0, a3 = 0;
        #pragma unroll
        for (int g = 0; g < 4; g++) {
            a0 += red[g][0][c]; a1 += red[g][1][c];
            a2 += red[g][2][c]; a3 += red[g][3][c];
        }
        atomicAdd(&stats[c], a0);
        atomicAdd(&stats[64 + c], a1);
        atomicAdd(&stats[128 + c], a2);
        atomicAdd(&stats[192 + c], a3);
    }
}

__global__ void k_bn1(float* __restrict__ stats, const float* __restrict__ g,
                      const float* __restrict__ b, int l) {
    int c = threadIdx.x;  // 128
    float mean = stats[c] * (1.0f / EE);
    float var = stats[128 + c] * (1.0f / EE) - mean * mean;
    float a = g[l * 128 + c] * rsqrtf(var + EPSV);
    stats[256 + c] = a;
    stats[384 + c] = b[l * 128 + c] - mean * a;
}

// ---------- edge pass 2: quad-edge gathers; gate + per-node accumulate + fused node-bn stats ----------
__global__ __launch_bounds__(256) void k_eapply(const unsigned* __restrict__ hs2p,
        const unsigned* __restrict__ hd2p, const unsigned* __restrict__ Tpl,
        const unsigned* __restrict__ epack, const int* __restrict__ offs,
        const float* __restrict__ stats, float* __restrict__ hacc,
        float* __restrict__ nstats) {
    int lane = threadIdx.x & 63, grp = threadIdx.x >> 6;
    int q = (lane >> 4) & 3, t = lane & 15;
    float a1[4], a2[4], b1[4], b2[4];
    #pragma unroll
    for (int k = 0; k < 4; k++) {
        a1[k] = stats[256 + t * 4 + k];
        a2[k] = stats[320 + t * 4 + k];
        b1[k] = stats[384 + t * 4 + k];
        b2[k] = stats[448 + t * 4 + k];
    }
    float ns[4] = {0, 0, 0, 0}, nq[4] = {0, 0, 0, 0};
    for (int v = blockIdx.x * 4 + grp; v < NN; v += gridDim.x * 4) {
        uint4 hdv = *(const uint4*)(hd2p + (size_t)v * 64 + t * 4);
        unsigned hda[4] = {hdv.x, hdv.y, hdv.z, hdv.w};
        float hd1[4], hd2c[4];
        #pragma unroll
        for (int k = 0; k < 4; k++) { hd1[k] = blo(hda[k]); hd2c[k] = bhi(hda[k]); }
        int e0 = offs[v], e1 = offs[v + 1];
        float accv[4] = {0, 0, 0, 0};
        for (int e = e0; e < e1; e += 8) {
            int eA = e + q, eB = eA + 4;
            unsigned epA = epack[(eA < e1) ? eA : (e1 - 1)];
            unsigned epB = epack[(eB < e1) ? eB : (e1 - 1)];
            uint4 hsA = *(const uint4*)(hs2p + (size_t)(epA >> 13) * 64 + t * 4);
            uint4 tA  = *(const uint4*)(Tpl + (size_t)(epA & 8191u) * 64 + t * 4);
            uint4 hsB = *(const uint4*)(hs2p + (size_t)(epB >> 13) * 64 + t * 4);
            uint4 tB  = *(const uint4*)(Tpl + (size_t)(epB & 8191u) * 64 + t * 4);
            float wA = (eA < e1) ? 1.0f : 0.0f;
            float wB = (eB < e1) ? 1.0f : 0.0f;
            unsigned ha[4] = {hsA.x, hsA.y, hsA.z, hsA.w};
            unsigned ta[4] = {tA.x, tA.y, tA.z, tA.w};
            unsigned hb[4] = {hsB.x, hsB.y, hsB.z, hsB.w};
            unsigned tb[4] = {tB.x, tB.y, tB.z, tB.w};
            #pragma unroll
            for (int k = 0; k < 4; k++) {
                float m1 = hd1[k] + blo(ha[k]) + blo(ta[k]);
                float m2 = hd2c[k] + bhi(ha[k]) + bhi(ta[k]);
                float g1 = fast_sig(fmaf(a1[k], m1, b1[k]));
                float g2 = fast_sp(fmaf(a2[k], m2, b2[k]));
                accv[k] = fmaf(wA * g1, g2, accv[k]);
                float n1 = hd1[k] + blo(hb[k]) + blo(tb[k]);
                float n2 = hd2c[k] + bhi(hb[k]) + bhi(tb[k]);
                float h1 = fast_sig(fmaf(a1[k], n1, b1[k]));
                float h2 = fast_sp(fmaf(a2[k], n2, b2[k]));
                accv[k] = fmaf(wB * h1, h2, accv[k]);
            }
        }
        // reduce the 4 edge-slots; lanes 0-15 hold cols t*4..t*4+3
        #pragma unroll
        for (int k = 0; k < 4; k++) {
            accv[k] += __shfl_down(accv[k], 32);
            accv[k] += __shfl_down(accv[k], 16);
        }
        if (lane < 16) {
            *(float4*)(hacc + (size_t)v * 64 + t * 4) =
                make_float4(accv[0], accv[1], accv[2], accv[3]);
            #pragma unroll
            for (int k = 0; k < 4; k++) {
                ns[k] += accv[k];
                nq[k] = fmaf(accv[k], accv[k], nq[k]);
            }
        }
    }
    __shared__ float red[4][2][64];
    if (lane < 16) {
        #pragma unroll
        for (int k = 0; k < 4; k++) {
            red[grp][0][t * 4 + k] = ns[k];
            red[grp][1][t * 4 + k] = nq[k];
        }
    }
    __syncthreads();
    if (threadIdx.x < 64) {
        int c = threadIdx.x;
        float a0 = 0, a1s = 0;
        #pragma unroll
        for (int g = 0; g < 4; g++) { a0 += red[g][0][c]; a1s += red[g][1][c]; }
        atomicAdd(&nstats[c], a0);
        atomicAdd(&nstats[64 + c], a1s);
    }
}

__global__ void k_bn2(float* __restrict__ nstats, const float* __restrict__ g,
                      const float* __restrict__ b, int l) {
    int c = threadIdx.x;  // 64
    float mean = nstats[c] * (1.0f / NN);
    float var = nstats[64 + c] * (1.0f / NN) - mean * mean;
    float a = g[l * 64 + c] * rsqrtf(var + EPSV);
    nstats[128 + c] = a;
    nstats[192 + c] = b[l * 64 + c] - mean * a;
}

// ---------- x = softplus(x + bn(hacc)) ----------
__global__ void k_update(float* __restrict__ x, const float* __restrict__ hacc,
                         const float* __restrict__ nstats) {
    int i = blockIdx.x * 4 + (threadIdx.x >> 6);
    int c = threadIdx.x & 63;
    float v = x[i * 64 + c] + fmaf(nstats[128 + c], hacc[i * 64 + c], nstats[192 + c]);
    x[i * 64 + c] = fmaxf(v, 0.0f) + log1pf(__expf(-fabsf(v)));
}

// ---------- readout ----------
__global__ void k_pool(const float* __restrict__ x, const int* __restrict__ gid,
                       float* __restrict__ pooled, float* __restrict__ counts) {
    int i = blockIdx.x * 4 + (threadIdx.x >> 6);
    int c = threadIdx.x & 63;
    int g = gid[i];
    atomicAdd(&pooled[g * 64 + c], x[i * 64 + c]);
    if (c == 0) atomicAdd(&counts[g], 1.0f);
}

__global__ void k_out(const float* __restrict__ pooled, const float* __restrict__ counts,
                      float* __restrict__ out) {
    int g = blockIdx.x, c = threadIdx.x;
    out[g * 64 + c] = pooled[g * 64 + c] / fmaxf(counts[g], 1.0f);
}

extern "C" void kernel_launch(void* const* d_in, const int* in_sizes, int n_in,
                              void* d_out, int out_size, void* d_ws, size_t ws_size,
                              hipStream_t stream) {
    const int* atom_types   = (const int*)d_in[0];
    const float* distances  = (const float*)d_in[1];
    const int* src          = (const int*)d_in[2];
    const int* dst          = (const int*)d_in[3];
    const int* gid          = (const int*)d_in[4];
    const float* atom_table = (const float*)d_in[6];
    const float* W_embed    = (const float*)d_in[7];
    const float* b_embed    = (const float*)d_in[8];
    const float* W_src      = (const float*)d_in[9];
    const float* b_src      = (const float*)d_in[10];
    const float* W_dst      = (const float*)d_in[11];
    const float* b_dst      = (const float*)d_in[12];
    const float* W_edge     = (const float*)d_in[13];
    const float* b_edge     = (const float*)d_in[14];
    const float* g_msg      = (const float*)d_in[15];
    const float* beta_msg   = (const float*)d_in[16];
    const float* g_bn       = (const float*)d_in[17];
    const float* beta_bn    = (const float*)d_in[18];
    float* out = (float*)d_out;

    float* ws = (float*)d_ws;
    float* x        = ws;                             // N*64 f32
    float* hacc     = x + (size_t)NN * 64;            // N*64 f32
    unsigned* hs2p  = (unsigned*)(hacc + (size_t)NN * 64);   // N*64 u32
    unsigned* hd2p  = hs2p + (size_t)NN * 64;         // N*64 u32
    unsigned* Tp    = hd2p + (size_t)NN * 64;         // 3*TB*64 u32
    unsigned* epack = Tp + (size_t)3 * TB * 64;       // EE u32
    float* emb      = (float*)(epack + (size_t)EE);   // 95*64
    float* stats    = emb + 95 * 64;                  // 512
    float* nstats   = stats + 512;                    // 256
    float* pooled   = nstats + 256;                   // G*64
    float* counts   = pooled + GG * 64;               // G
    int* deg        = (int*)(counts + GG);            // N
    int* offs       = deg + NN;                       // N+1
    int* cursor     = offs + NN + 1;                  // N
    int* csum       = cursor + NN;                    // 128
    int* cbase      = csum + 128;                     // 130

    const int NCH = (NN + 1023) / 1024;  // 98

    k_emb<<<95, 64, 0, stream>>>(atom_table, W_embed, b_embed, emb);
    k_table<<<dim3(TB, 3), 64, 0, stream>>>(W_edge, b_edge, Tp);
    k_ninit<<<NN / 4, 256, 0, stream>>>(atom_types, emb, x);

    hipMemsetAsync(deg, 0, NN * sizeof(int), stream);
    k_hist<<<(EE + 255) / 256, 256, 0, stream>>>(dst, deg);
    k_scanA<<<NCH, 1024, 0, stream>>>(deg, offs, csum);
    k_scanB<<<1, 128, 0, stream>>>(csum, cbase, NCH);
    k_scanC<<<(NN + 255) / 256, 256, 0, stream>>>(offs, cbase, csum, NCH);
    hipMemcpyAsync(cursor, offs, NN * sizeof(int), hipMemcpyDeviceToDevice, stream);
    k_scatter<<<(EE + 255) / 256, 256, 0, stream>>>(src, dst, distances, cursor, epack);

    for (int l = 0; l < 3; l++) {
        hipMemsetAsync(stats, 0, (768 + 256) * sizeof(float), stream);
        k_gemm<<<512, 256, 0, stream>>>(x, W_src, b_src, W_dst, b_dst, hs2p, hd2p, l);
        const unsigned* Tpl = Tp + (size_t)l * TB * 64;
        k_estats<<<4096, 256, 0, stream>>>(hs2p, hd2p, Tpl, epack, offs, stats);
        k_bn1<<<1, 128, 0, stream>>>(stats, g_msg, beta_msg, l);
        k_eapply<<<4096, 256, 0, stream>>>(hs2p, hd2p, Tpl, epack, offs, stats, hacc, nstats);
        k_bn2<<<1, 64, 0, stream>>>(nstats, g_bn, beta_bn, l);
        k_update<<<NN / 4, 256, 0, stream>>>(x, hacc, nstats);
    }

    hipMemsetAsync(pooled, 0, (GG * 64 + GG) * sizeof(float), stream);
    k_pool<<<NN / 4, 256, 0, stream>>>(x, gid, pooled, counts);
    k_out<<<GG, 64, 0, stream>>>(pooled, counts, out);
}